// Round 2
// baseline (1718.836 us; speedup 1.0000x reference)
//
#include <hip/hip_runtime.h>
#include <cstdint>
#include <cstddef>

// Problem dims
#define Bb  512
#define Ss  36
#define Hh  1024
#define AHh 512

__device__ __forceinline__ float fsig(float x)  { return 1.0f / (1.0f + __expf(-x)); }
__device__ __forceinline__ float ftanh(float x) { return 1.0f - 2.0f / (__expf(2.0f * x) + 1.0f); }

// ---------------- segmented-K tiled fp32 GEMM ----------------
// C = A(MxK) @ B(NxK)^T + bias0 [+ bias1], then activation.
// A is a virtual concat of up to 4 column segments; B of up to 2 (for fused
// Wih/Whh). Segment boundaries are multiples of 1024 >> 16 (K-tile), so the
// per-tile segment choice is block-uniform.
// ACT: 0 = none, 1 = relu, 2 = sigmoid(relu(x))
struct ASegs {
    const float* p[4];
    int ld[4];
    int off[4];
    int kb[3];   // k-boundaries after seg0, seg1, seg2 (unused -> K)
};
struct BSegs {
    const float* p[2];
    int ld[2];
    int kb;      // boundary after seg0 (unused -> K)
};

template<int ACT>
__global__ __launch_bounds__(256) void gemm_seg(
    ASegs AS, BSegs BS,
    const float* __restrict__ bias0, const float* __restrict__ bias1,
    float* __restrict__ C, int M, int N, int K)
{
    __shared__ float As[16][68];   // 68: 16B-aligned row stride, <=2-way banks
    __shared__ float Bs[16][68];
    const int tid = threadIdx.x;
    const int tx = tid & 15, ty = tid >> 4;
    const int m0 = blockIdx.x * 64, n0 = blockIdx.y * 64;
    const int lk = tid & 15, lr = tid >> 4;
    float acc[4][4] = {};
    for (int k0 = 0; k0 < K; k0 += 16) {
        // block-uniform segment select
        const float* Ap; int ald, aoff, kla;
        if      (k0 < AS.kb[0]) { Ap = AS.p[0]; ald = AS.ld[0]; aoff = AS.off[0]; kla = k0; }
        else if (k0 < AS.kb[1]) { Ap = AS.p[1]; ald = AS.ld[1]; aoff = AS.off[1]; kla = k0 - AS.kb[0]; }
        else if (k0 < AS.kb[2]) { Ap = AS.p[2]; ald = AS.ld[2]; aoff = AS.off[2]; kla = k0 - AS.kb[1]; }
        else                    { Ap = AS.p[3]; ald = AS.ld[3]; aoff = AS.off[3]; kla = k0 - AS.kb[2]; }
        const float* Bp; int bld, klb;
        if (k0 < BS.kb) { Bp = BS.p[0]; bld = BS.ld[0]; klb = k0; }
        else            { Bp = BS.p[1]; bld = BS.ld[1]; klb = k0 - BS.kb; }
#pragma unroll
        for (int i = 0; i < 4; ++i) {
            int m = lr + i * 16;
            As[lk][m] = Ap[(size_t)(m0 + m) * ald + aoff + kla + lk];
            Bs[lk][m] = Bp[(size_t)(n0 + m) * bld + klb + lk];
        }
        __syncthreads();
#pragma unroll
        for (int k = 0; k < 16; ++k) {
            float a[4], b[4];
#pragma unroll
            for (int i = 0; i < 4; ++i) a[i] = As[k][ty * 4 + i];
#pragma unroll
            for (int j = 0; j < 4; ++j) b[j] = Bs[k][tx * 4 + j];
#pragma unroll
            for (int i = 0; i < 4; ++i)
#pragma unroll
                for (int j = 0; j < 4; ++j)
                    acc[i][j] = fmaf(a[i], b[j], acc[i][j]);
        }
        __syncthreads();
    }
#pragma unroll
    for (int i = 0; i < 4; ++i) {
        int m = m0 + ty * 4 + i;
        int n = n0 + tx * 4;
        float4 v;
        v.x = acc[i][0]; v.y = acc[i][1]; v.z = acc[i][2]; v.w = acc[i][3];
        const float4 bv = *(const float4*)&bias0[n];
        v.x += bv.x; v.y += bv.y; v.z += bv.z; v.w += bv.w;
        if (bias1) {
            const float4 b2 = *(const float4*)&bias1[n];
            v.x += b2.x; v.y += b2.y; v.z += b2.z; v.w += b2.w;
        }
        if (ACT == 1) {
            v.x = fmaxf(v.x, 0.f); v.y = fmaxf(v.y, 0.f);
            v.z = fmaxf(v.z, 0.f); v.w = fmaxf(v.w, 0.f);
        }
        if (ACT == 2) {
            v.x = fsig(fmaxf(v.x, 0.f)); v.y = fsig(fmaxf(v.y, 0.f));
            v.z = fsig(fmaxf(v.z, 0.f)); v.w = fsig(fmaxf(v.w, 0.f));
        }
        *(float4*)&C[(size_t)m * N + n] = v;
    }
}

// ---------------- batched 4-branch h2att GEMM: ATTH[z] = h_att @ W[z]^T + b[z]
__global__ __launch_bounds__(256) void gemm_atth_k(
    const float* __restrict__ h_att,
    const float* W0, const float* W1, const float* W2, const float* W3,
    const float* b0, const float* b1, const float* b2, const float* b3,
    float* __restrict__ ATTH)
{
    const int z = blockIdx.z;
    const float* Bw   = z == 0 ? W0 : z == 1 ? W1 : z == 2 ? W2 : W3;
    const float* bias = z == 0 ? b0 : z == 1 ? b1 : z == 2 ? b2 : b3;
    float* C = ATTH + (size_t)z * Bb * AHh;
    const int M = Bb, N = AHh, K = Hh;

    __shared__ float As[16][68];
    __shared__ float Bs[16][68];
    const int tid = threadIdx.x;
    const int tx = tid & 15, ty = tid >> 4;
    const int m0 = blockIdx.x * 64, n0 = blockIdx.y * 64;
    const int lk = tid & 15, lr = tid >> 4;
    float acc[4][4] = {};
    for (int k0 = 0; k0 < K; k0 += 16) {
#pragma unroll
        for (int i = 0; i < 4; ++i) {
            int m = lr + i * 16;
            As[lk][m] = h_att[(size_t)(m0 + m) * K + k0 + lk];
            Bs[lk][m] = Bw[(size_t)(n0 + m) * K + k0 + lk];
        }
        __syncthreads();
#pragma unroll
        for (int k = 0; k < 16; ++k) {
            float a[4], b[4];
#pragma unroll
            for (int i = 0; i < 4; ++i) a[i] = As[k][ty * 4 + i];
#pragma unroll
            for (int j = 0; j < 4; ++j) b[j] = Bs[k][tx * 4 + j];
#pragma unroll
            for (int i = 0; i < 4; ++i)
#pragma unroll
                for (int j = 0; j < 4; ++j)
                    acc[i][j] = fmaf(a[i], b[j], acc[i][j]);
        }
        __syncthreads();
    }
#pragma unroll
    for (int i = 0; i < 4; ++i) {
        int m = m0 + ty * 4 + i;
        int n = n0 + tx * 4;
        float4 v;
        v.x = acc[i][0]; v.y = acc[i][1]; v.z = acc[i][2]; v.w = acc[i][3];
        const float4 bv = *(const float4*)&bias[n];
        v.x += bv.x; v.y += bv.y; v.z += bv.z; v.w += bv.w;
        *(float4*)&C[(size_t)m * N + n] = v;
    }
}

// ---------------- LSTM elementwise: gates g (B,4096) order i,f,g,o
__global__ __launch_bounds__(256) void lstm_cell_k(
    const float* __restrict__ g, const float* __restrict__ c_prev,
    float* __restrict__ h_out, float* __restrict__ c_out, float* __restrict__ h_out2)
{
    int idx = blockIdx.x * 256 + threadIdx.x;   // Bb*Hh
    int b = idx >> 10, d = idx & 1023;
    const float* gb = g + (size_t)b * 4096;
    float gi = gb[d], gf = gb[1024 + d], gc = gb[2048 + d], go = gb[3072 + d];
    float c2 = fsig(gf) * c_prev[idx] + fsig(gi) * ftanh(gc);
    float h2 = fsig(go) * ftanh(c2);
    c_out[idx] = c2;
    h_out[idx] = h2;
    if (h_out2) h_out2[idx] = h2;
}

// ---------------- fused attention: scores + softmax(+mask renorm) + weighted sum
// block = (b, branch); 256 threads
struct AttPtrs {
    const float* p_att[4];
    const float* feats[4];
    const float* mask[4];
    const float* aW[4];
    const float* ab[4];
};
__global__ __launch_bounds__(256) void att_fused_k(
    AttPtrs P, const float* __restrict__ atth_all, float* __restrict__ out_all)
{
    const int b = blockIdx.x, br = blockIdx.y;
    const int tid = threadIdx.x, lane = tid & 63, w = tid >> 6;
    const float* atth  = atth_all + ((size_t)br * Bb + b) * AHh;
    const float* p     = P.p_att[br] + (size_t)b * Ss * AHh;
    const float* feats = P.feats[br] + (size_t)b * Ss * Hh;
    const float* mask  = P.mask[br] + (size_t)b * Ss;
    float* outp = out_all + ((size_t)br * Bb + b) * Hh;

    __shared__ float sc[Ss];
    __shared__ float wsm[Ss];

    // phase A: scores. s handled by wave w: s = w, w+4, ...
    const float4* h4 = (const float4*)atth;
    const float4* a4 = (const float4*)P.aW[br];
    float4 hv0 = h4[lane], hv1 = h4[lane + 64];
    float4 av0 = a4[lane], av1 = a4[lane + 64];
    float ab0 = P.ab[br][0];
    for (int s = w; s < Ss; s += 4) {
        const float4* p4 = (const float4*)(p + (size_t)s * AHh);
        float4 pv0 = p4[lane], pv1 = p4[lane + 64];
        float sum = ftanh(pv0.x + hv0.x) * av0.x
                  + ftanh(pv0.y + hv0.y) * av0.y
                  + ftanh(pv0.z + hv0.z) * av0.z
                  + ftanh(pv0.w + hv0.w) * av0.w
                  + ftanh(pv1.x + hv1.x) * av1.x
                  + ftanh(pv1.y + hv1.y) * av1.y
                  + ftanh(pv1.z + hv1.z) * av1.z
                  + ftanh(pv1.w + hv1.w) * av1.w;
#pragma unroll
        for (int off = 32; off > 0; off >>= 1) sum += __shfl_xor(sum, off);
        if (lane == 0) sc[s] = sum + ab0;
    }
    __syncthreads();

    // phase B: softmax (serial over 36, redundant per thread — LDS broadcast)
    float mx = -1e30f;
#pragma unroll
    for (int s = 0; s < Ss; ++s) mx = fmaxf(mx, sc[s]);
    float den = 0.f;
#pragma unroll
    for (int s = 0; s < Ss; ++s) den += __expf(sc[s] - mx);
    if (tid < Ss) wsm[tid] = __expf(sc[tid] - mx) / den * mask[tid];
    __syncthreads();
    float s2 = 0.f;
#pragma unroll
    for (int s = 0; s < Ss; ++s) s2 += wsm[s];
    const float inv = 1.f / (s2 + 1e-10f);

    // phase C: weighted sum; thread t owns float4 at d=4t
    const float4* f4 = (const float4*)feats;
    float4 acc = {0.f, 0.f, 0.f, 0.f};
#pragma unroll 6
    for (int s = 0; s < Ss; ++s) {
        float wv = wsm[s];
        float4 v = f4[s * 256 + tid];
        acc.x = fmaf(wv, v.x, acc.x);
        acc.y = fmaf(wv, v.y, acc.y);
        acc.z = fmaf(wv, v.z, acc.z);
        acc.w = fmaf(wv, v.w, acc.w);
    }
    acc.x *= inv; acc.y *= inv; acc.z *= inv; acc.w *= inv;
    ((float4*)outp)[tid] = acc;
}

// ---------------- human mean: out[b,d] = sum_p hf[b,p,d] / (sum_p bm[b,p] + 1e-10)
__global__ __launch_bounds__(256) void human_mean_k(
    const float* __restrict__ hf, const float* __restrict__ bm,
    float* __restrict__ out)
{
    int idx = blockIdx.x * 256 + threadIdx.x;   // Bb*Hh
    int b = idx >> 10, d = idx & 1023;
    float s = 0.f;
#pragma unroll
    for (int p = 0; p < 6; ++p) s += hf[((size_t)b * 6 + p) * Hh + d];
    float ms = 0.f;
#pragma unroll
    for (int p = 0; p < 6; ++p) ms += bm[b * 6 + p];
    out[idx] = s / (ms + 1e-10f);
}

// ---------------- final combine: a_ori = (a_act + cal2)*g_h + a_obj*g_o + a_ori
__global__ __launch_bounds__(256) void combine_k(
    const float* __restrict__ a_act, const float* __restrict__ cal2,
    const float* __restrict__ g_h, const float* __restrict__ a_obj,
    const float* __restrict__ g_o, float* a_ori)
{
    int idx = blockIdx.x * 256 + threadIdx.x;
    float att_human = a_act[idx] + cal2[idx];
    a_ori[idx] = att_human * g_h[idx] + a_obj[idx] * g_o[idx] + a_ori[idx];
}

// ---------------- helpers to build segment descriptors ----------------
static inline ASegs aseg1(const float* p, int ld, int off, int K) {
    ASegs s; for (int i = 0; i < 4; ++i) { s.p[i] = p; s.ld[i] = ld; s.off[i] = off; }
    s.kb[0] = K; s.kb[1] = K; s.kb[2] = K; return s;
}
static inline ASegs aseg2(const float* p0, int ld0, int off0, int k1,
                          const float* p1, int ld1, int off1, int K) {
    ASegs s = aseg1(p0, ld0, off0, K);
    s.p[1] = p1; s.ld[1] = ld1; s.off[1] = off1;
    s.kb[0] = k1; s.kb[1] = K; s.kb[2] = K;
    s.p[2] = p1; s.ld[2] = ld1; s.off[2] = off1;
    s.p[3] = p1; s.ld[3] = ld1; s.off[3] = off1;
    return s;
}
static inline BSegs bseg1(const float* p, int ld, int K) {
    BSegs s; s.p[0] = p; s.p[1] = p; s.ld[0] = ld; s.ld[1] = ld; s.kb = K; return s;
}

extern "C" void kernel_launch(void* const* d_in, const int* in_sizes, int n_in,
                              void* d_out, int out_size, void* d_ws, size_t ws_size,
                              hipStream_t stream)
{
    (void)in_sizes; (void)n_in; (void)out_size; (void)ws_size;

    const float* xt = (const float*)d_in[0];
    const float* fc = (const float*)d_in[1];
    const float* att_feats[4] = {(const float*)d_in[2], (const float*)d_in[4],
                                 (const float*)d_in[6], (const float*)d_in[8]};
    const float* p_att[4]     = {(const float*)d_in[3], (const float*)d_in[5],
                                 (const float*)d_in[7], (const float*)d_in[9]};
    // mpm attention uses att_masks_ori (index 12) — per reference
    const float* masks[4]     = {(const float*)d_in[10], (const float*)d_in[11],
                                 (const float*)d_in[12], (const float*)d_in[12]};
    const float* human_feats = (const float*)d_in[13];
    const float* body_masks  = (const float*)d_in[14];
    const float* state_h = (const float*)d_in[15];
    const float* state_c = (const float*)d_in[16];
    const float* W_ih_att  = (const float*)d_in[17];
    const float* W_hh_att  = (const float*)d_in[18];
    const float* b_ih_att  = (const float*)d_in[19];
    const float* b_hh_att  = (const float*)d_in[20];
    const float* W_ih_lang = (const float*)d_in[21];
    const float* W_hh_lang = (const float*)d_in[22];
    const float* b_ih_lang = (const float*)d_in[23];
    const float* b_hh_lang = (const float*)d_in[24];
    const float* h2W[4] = {(const float*)d_in[25], (const float*)d_in[29],
                           (const float*)d_in[33], (const float*)d_in[37]};
    const float* h2b[4] = {(const float*)d_in[26], (const float*)d_in[30],
                           (const float*)d_in[34], (const float*)d_in[38]};
    const float* aWp[4] = {(const float*)d_in[27], (const float*)d_in[31],
                           (const float*)d_in[35], (const float*)d_in[39]};
    const float* abp[4] = {(const float*)d_in[28], (const float*)d_in[32],
                           (const float*)d_in[36], (const float*)d_in[40]};
    const float* hg_W = (const float*)d_in[41];
    const float* hg_b = (const float*)d_in[42];
    const float* ng_W = (const float*)d_in[43];
    const float* ng_b = (const float*)d_in[44];
    const float* c1W  = (const float*)d_in[45];
    const float* c1b  = (const float*)d_in[46];
    const float* c2W  = (const float*)d_in[47];
    const float* c2b  = (const float*)d_in[48];

    const int BH = Bb * Hh;
    float* out    = (float*)d_out;               // h_lang copy (output #1)
    float* h_att  = out + (size_t)BH;
    float* h_lang = out + (size_t)2 * BH;
    float* c_att  = out + (size_t)3 * BH;
    float* c_lang = out + (size_t)4 * BH;

    float* ws = (float*)d_ws;
    float* G      = ws; ws += (size_t)Bb * 4096;     // LSTM gates
    float* ATTH4  = ws; ws += (size_t)4 * Bb * AHh;  // 4 branches of att_h
    float* abuf   = ws; ws += (size_t)4 * BH;        // 4 attention outputs (contiguous)
    float* gate_h = ws; ws += (size_t)BH;
    float* gate_o = ws; ws += (size_t)BH;
    float* part0  = ws; ws += (size_t)BH;
    float* cal1   = ws; ws += (size_t)BH;
    float* cal2   = ws; ws += (size_t)BH;

    const float* h0     = state_h;                 // state_h[0]
    const float* prev_h = state_h + (size_t)BH;    // state_h[1] (= state_h[-1])
    const float* c0     = state_c;
    const float* c1     = state_c + (size_t)BH;

    // ---- attention LSTM: G = [prev_h, fc_ori, xt] @ Wih^T + h0 @ Whh^T + biases
    {
        ASegs A;
        A.p[0] = prev_h;    A.ld[0] = Hh;   A.off[0] = 0;
        A.p[1] = fc;        A.ld[1] = 3072; A.off[1] = 0;
        A.p[2] = xt;        A.ld[2] = Hh;   A.off[2] = 0;
        A.p[3] = h0;        A.ld[3] = Hh;   A.off[3] = 0;
        A.kb[0] = 1024; A.kb[1] = 2048; A.kb[2] = 3072;
        BSegs Bg;
        Bg.p[0] = W_ih_att; Bg.ld[0] = 3072; Bg.p[1] = W_hh_att; Bg.ld[1] = 1024; Bg.kb = 3072;
        gemm_seg<0><<<dim3(8, 64), 256, 0, stream>>>(A, Bg, b_ih_att, b_hh_att, G, Bb, 4096, 4096);
    }
    lstm_cell_k<<<2048, 256, 0, stream>>>(G, c0, h_att, c_att, nullptr);

    // ---- human feats mean (independent)
    human_mean_k<<<2048, 256, 0, stream>>>(human_feats, body_masks, part0);

    // ---- batched h2att GEMMs for 4 branches
    gemm_atth_k<<<dim3(8, 8, 4), 256, 0, stream>>>(
        h_att, h2W[0], h2W[1], h2W[2], h2W[3],
        h2b[0], h2b[1], h2b[2], h2b[3], ATTH4);

    // ---- fused attention (scores + softmax + mask renorm + weighted sum), 4 branches
    {
        AttPtrs P;
        for (int i = 0; i < 4; ++i) {
            P.p_att[i] = p_att[i]; P.feats[i] = att_feats[i];
            P.mask[i] = masks[i]; P.aW[i] = aWp[i]; P.ab[i] = abp[i];
        }
        att_fused_k<<<dim3(Bb, 4), 256, 0, stream>>>(P, ATTH4, abuf);
    }

    // ---- gate_human = sigmoid(relu([fc_act, h_att] @ hg_W^T + b))
    gemm_seg<2><<<dim3(8, 16), 256, 0, stream>>>(
        aseg2(fc, 3072, 1024, 1024, h_att, Hh, 0, 2048), bseg1(hg_W, 2048, 2048),
        hg_b, nullptr, gate_h, Bb, Hh, 2048);

    // ---- gate_obj = sigmoid(relu([fc_back, h_att] @ ng_W^T + b))
    gemm_seg<2><<<dim3(8, 16), 256, 0, stream>>>(
        aseg2(fc, 3072, 2048, 1024, h_att, Hh, 0, 2048), bseg1(ng_W, 2048, 2048),
        ng_b, nullptr, gate_o, Bb, Hh, 2048);

    // ---- cali: cal1 = relu([part0, att_activity] @ c1W^T + b); cal2 = cal1 @ c2W^T + b
    gemm_seg<1><<<dim3(8, 16), 256, 0, stream>>>(
        aseg2(part0, Hh, 0, 1024, abuf /*att_activity*/, Hh, 0, 2048), bseg1(c1W, 2048, 2048),
        c1b, nullptr, cal1, Bb, Hh, 2048);
    gemm_seg<0><<<dim3(8, 16), 256, 0, stream>>>(
        aseg1(cal1, Hh, 0, 1024), bseg1(c2W, 1024, 1024),
        c2b, nullptr, cal2, Bb, Hh, 1024);

    // ---- att_ori_final = (att_act + cal2)*gate_h + att_obj*gate_o + att_ori
    combine_k<<<2048, 256, 0, stream>>>(
        abuf /*act*/, cal2, gate_h, abuf + BH /*back*/, gate_o, abuf + 2 * (size_t)BH /*ori*/);

    // ---- language LSTM: G = [att_mpm, att_ori_final, h_att] @ Wih^T + prev_h @ Whh^T + biases
    {
        ASegs A;
        A.p[0] = abuf + 3 * (size_t)BH; A.ld[0] = Hh; A.off[0] = 0;   // att_mpm
        A.p[1] = abuf + 2 * (size_t)BH; A.ld[1] = Hh; A.off[1] = 0;   // att_ori_final
        A.p[2] = h_att;                 A.ld[2] = Hh; A.off[2] = 0;
        A.p[3] = prev_h;                A.ld[3] = Hh; A.off[3] = 0;   // state_h[1]
        A.kb[0] = 1024; A.kb[1] = 2048; A.kb[2] = 3072;
        BSegs Bg;
        Bg.p[0] = W_ih_lang; Bg.ld[0] = 3072; Bg.p[1] = W_hh_lang; Bg.ld[1] = 1024; Bg.kb = 3072;
        gemm_seg<0><<<dim3(8, 64), 256, 0, stream>>>(A, Bg, b_ih_lang, b_hh_lang, G, Bb, 4096, 4096);
    }
    lstm_cell_k<<<2048, 256, 0, stream>>>(G, c1, h_lang, c_lang, out);
}

// Round 3
// 993.122 us; speedup vs baseline: 1.7307x; 1.7307x over previous
//
#include <hip/hip_runtime.h>
#include <hip/hip_bf16.h>
#include <cstdint>
#include <cstddef>

// Problem dims
#define Bb  512
#define Ss  36
#define Hh  1024
#define AHh 512

typedef short short8 __attribute__((ext_vector_type(8)));
typedef float f32x4 __attribute__((ext_vector_type(4)));

__device__ __forceinline__ float fsig(float x)  { return 1.0f / (1.0f + __expf(-x)); }
__device__ __forceinline__ float ftanh(float x) { return 1.0f - 2.0f / (__expf(2.0f * x) + 1.0f); }

// ---------------- segment descriptor (column-concat of fp32 sources) ----------------
struct ASegs {
    const float* p[4];
    int ld[4];
    int off[4];
    int kb[3];   // column boundaries after seg0, seg1, seg2 (unused -> C)
};
static inline ASegs aseg1(const float* p, int ld, int off, int C) {
    ASegs s; for (int i = 0; i < 4; ++i) { s.p[i] = p; s.ld[i] = ld; s.off[i] = off; }
    s.kb[0] = C; s.kb[1] = C; s.kb[2] = C; return s;
}
static inline ASegs aseg2(const float* p0, int ld0, int off0, int k1,
                          const float* p1, int ld1, int off1, int C) {
    ASegs s = aseg1(p0, ld0, off0, C);
    s.p[1] = p1; s.ld[1] = ld1; s.off[1] = off1;
    s.p[2] = p1; s.ld[2] = ld1; s.off[2] = off1;
    s.p[3] = p1; s.ld[3] = ld1; s.off[3] = off1;
    s.kb[0] = k1;
    return s;
}
static inline ASegs aseg4(const float* p0, const float* p1, const float* p2, const float* p3,
                          int ld0, int ld1, int ld2, int ld3,
                          int o0, int o1, int o2, int o3) {
    ASegs s;
    s.p[0] = p0; s.p[1] = p1; s.p[2] = p2; s.p[3] = p3;
    s.ld[0] = ld0; s.ld[1] = ld1; s.ld[2] = ld2; s.ld[3] = ld3;
    s.off[0] = o0; s.off[1] = o1; s.off[2] = o2; s.off[3] = o3;
    s.kb[0] = 1024; s.kb[1] = 2048; s.kb[2] = 3072;
    return s;
}

// ---------------- fp32 -> bf16 convert + column-concat pack ----------------
// dst (R x C) bf16 row-major; sources are fp32 column segments (boundaries
// multiples of 1024, so an 8-wide chunk never crosses a boundary).
__global__ __launch_bounds__(256) void cvt_cat_bf16(
    ASegs AS, __hip_bfloat16* __restrict__ dst, int R, int C8)
{
    int idx = blockIdx.x * 256 + threadIdx.x;
    if (idx >= R * C8) return;
    int r = idx / C8, cc = (idx - r * C8) * 8;
    const float* p; int ld, off, c0;
    if      (cc < AS.kb[0]) { p = AS.p[0]; ld = AS.ld[0]; off = AS.off[0]; c0 = cc; }
    else if (cc < AS.kb[1]) { p = AS.p[1]; ld = AS.ld[1]; off = AS.off[1]; c0 = cc - AS.kb[0]; }
    else if (cc < AS.kb[2]) { p = AS.p[2]; ld = AS.ld[2]; off = AS.off[2]; c0 = cc - AS.kb[1]; }
    else                    { p = AS.p[3]; ld = AS.ld[3]; off = AS.off[3]; c0 = cc - AS.kb[2]; }
    const float4* s = (const float4*)(p + (size_t)r * ld + off + c0);
    float4 v0 = s[0], v1 = s[1];
    short8 o;
    o[0] = (short)__bfloat16_as_ushort(__float2bfloat16(v0.x));
    o[1] = (short)__bfloat16_as_ushort(__float2bfloat16(v0.y));
    o[2] = (short)__bfloat16_as_ushort(__float2bfloat16(v0.z));
    o[3] = (short)__bfloat16_as_ushort(__float2bfloat16(v0.w));
    o[4] = (short)__bfloat16_as_ushort(__float2bfloat16(v1.x));
    o[5] = (short)__bfloat16_as_ushort(__float2bfloat16(v1.y));
    o[6] = (short)__bfloat16_as_ushort(__float2bfloat16(v1.z));
    o[7] = (short)__bfloat16_as_ushort(__float2bfloat16(v1.w));
    *(short8*)&dst[(size_t)r * (C8 * 8) + cc] = o;
}

// ---------------- tiny bias helpers ----------------
__global__ __launch_bounds__(256) void bias_sum_k(
    const float* __restrict__ a, const float* __restrict__ b, float* __restrict__ o, int n)
{
    int i = blockIdx.x * 256 + threadIdx.x;
    if (i < n) o[i] = a[i] + b[i];
}
__global__ __launch_bounds__(256) void bias_cat4_k(
    const float* b0, const float* b1, const float* b2, const float* b3, float* __restrict__ o)
{
    int i = blockIdx.x * 256 + threadIdx.x;   // 2048
    const float* s = (i >> 9) == 0 ? b0 : (i >> 9) == 1 ? b1 : (i >> 9) == 2 ? b2 : b3;
    o[i] = s[i & 511];
}

// ---------------- MFMA bf16 GEMM: C = A(MxK) @ Bw(NxK)^T + bias, activation ----------------
// 256 threads = 4 waves in 2x2; wave tile (BM/2 x BN/2); 16x16x32 bf16 MFMA.
// ACT: 0 none, 1 relu, 2 sigmoid(relu). OBF: write bf16 instead of fp32.
template<int R>
__device__ __forceinline__ void stage_tile(
    const __hip_bfloat16* __restrict__ src, int ld, int r0, int k0,
    short* lds, int w, int lane)
{
#pragma unroll
    for (int i = 0; i < R / 64; ++i) {
        int cid = w * R + i * 64 + lane;          // 16B chunk id
        int row = cid >> 2, ch = cid & 3;
        const __hip_bfloat16* g = src + (size_t)(r0 + row) * ld + k0 + ch * 8;
        char* l = (char*)lds + (size_t)(w * R + i * 64) * 16;
        __builtin_amdgcn_global_load_lds(
            (const __attribute__((address_space(1))) void*)g,
            (__attribute__((address_space(3))) void*)l, 16, 0, 0);
    }
}

template<int BM, int BN, int ACT, int OBF>
__global__ __launch_bounds__(256) void gemm_mfma(
    const __hip_bfloat16* __restrict__ A, const __hip_bfloat16* __restrict__ Bw,
    const float* __restrict__ bias, float* __restrict__ C,
    __hip_bfloat16* __restrict__ Cbf, int M, int N, int K)
{
    __shared__ short As[BM * 32];
    __shared__ short Bs[BN * 32];
    const int tid = threadIdx.x, w = tid >> 6, lane = tid & 63;
    const int wr = w >> 1, wc = w & 1;
    constexpr int FM = BM / 32, FN = BN / 32;
    const int m0 = blockIdx.x * BM, n0 = blockIdx.y * BN;
    const int rbase = wr * (BM / 2), cbase = wc * (BN / 2);
    const int lrow = lane & 15, kb = (lane >> 4) * 8;

    f32x4 acc[FM][FN] = {};
    for (int k0 = 0; k0 < K; k0 += 32) {
        stage_tile<BM>(A,  K, m0, k0, As, w, lane);
        stage_tile<BN>(Bw, K, n0, k0, Bs, w, lane);
        __syncthreads();
        short8 af[FM], bf[FN];
#pragma unroll
        for (int mi = 0; mi < FM; ++mi)
            af[mi] = *(const short8*)&As[(rbase + mi * 16 + lrow) * 32 + kb];
#pragma unroll
        for (int ni = 0; ni < FN; ++ni)
            bf[ni] = *(const short8*)&Bs[(cbase + ni * 16 + lrow) * 32 + kb];
#pragma unroll
        for (int mi = 0; mi < FM; ++mi)
#pragma unroll
            for (int ni = 0; ni < FN; ++ni)
                acc[mi][ni] = __builtin_amdgcn_mfma_f32_16x16x32_bf16(
                    af[mi], bf[ni], acc[mi][ni], 0, 0, 0);
        __syncthreads();
    }
#pragma unroll
    for (int ni = 0; ni < FN; ++ni) {
        int col = n0 + cbase + ni * 16 + (lane & 15);
        float bv = bias[col];
#pragma unroll
        for (int mi = 0; mi < FM; ++mi) {
#pragma unroll
            for (int r = 0; r < 4; ++r) {
                int row = m0 + rbase + mi * 16 + (lane >> 4) * 4 + r;
                float v = acc[mi][ni][r] + bv;
                if (ACT == 1) v = fmaxf(v, 0.f);
                if (ACT == 2) v = fsig(fmaxf(v, 0.f));
                if (OBF) Cbf[(size_t)row * N + col] = __float2bfloat16(v);
                else     C[(size_t)row * N + col] = v;
            }
        }
    }
}

// ---------------- LSTM elementwise: gates g (B,4096) order i,f,g,o
__global__ __launch_bounds__(256) void lstm_cell_k(
    const float* __restrict__ g, const float* __restrict__ c_prev,
    float* __restrict__ h_out, float* __restrict__ c_out,
    float* __restrict__ h_out2, __hip_bfloat16* __restrict__ h_bf)
{
    int idx = blockIdx.x * 256 + threadIdx.x;   // Bb*Hh
    int b = idx >> 10, d = idx & 1023;
    const float* gb = g + (size_t)b * 4096;
    float gi = gb[d], gf = gb[1024 + d], gc = gb[2048 + d], go = gb[3072 + d];
    float c2 = fsig(gf) * c_prev[idx] + fsig(gi) * ftanh(gc);
    float h2 = fsig(go) * ftanh(c2);
    c_out[idx] = c2;
    h_out[idx] = h2;
    if (h_out2) h_out2[idx] = h2;
    if (h_bf)   h_bf[idx] = __float2bfloat16(h2);
}

// ---------------- fused attention: scores + softmax(+mask renorm) + weighted sum
// block = (b, branch); 256 threads. ATTH layout: [b][br*512 + a] (b-major, 2048 wide)
struct AttPtrs {
    const float* p_att[4];
    const float* feats[4];
    const float* mask[4];
    const float* aW[4];
    const float* ab[4];
};
__global__ __launch_bounds__(256) void att_fused_k(
    AttPtrs P, const float* __restrict__ atth_all, float* __restrict__ out_all)
{
    const int b = blockIdx.x, br = blockIdx.y;
    const int tid = threadIdx.x, lane = tid & 63, w = tid >> 6;
    const float* atth  = atth_all + (size_t)b * 2048 + br * 512;
    const float* p     = P.p_att[br] + (size_t)b * Ss * AHh;
    const float* feats = P.feats[br] + (size_t)b * Ss * Hh;
    const float* mask  = P.mask[br] + (size_t)b * Ss;
    float* outp = out_all + ((size_t)br * Bb + b) * Hh;

    __shared__ float sc[Ss];
    __shared__ float wsm[Ss];

    const float4* h4 = (const float4*)atth;
    const float4* a4 = (const float4*)P.aW[br];
    float4 hv0 = h4[lane], hv1 = h4[lane + 64];
    float4 av0 = a4[lane], av1 = a4[lane + 64];
    float ab0 = P.ab[br][0];
    for (int s = w; s < Ss; s += 4) {
        const float4* p4 = (const float4*)(p + (size_t)s * AHh);
        float4 pv0 = p4[lane], pv1 = p4[lane + 64];
        float sum = ftanh(pv0.x + hv0.x) * av0.x
                  + ftanh(pv0.y + hv0.y) * av0.y
                  + ftanh(pv0.z + hv0.z) * av0.z
                  + ftanh(pv0.w + hv0.w) * av0.w
                  + ftanh(pv1.x + hv1.x) * av1.x
                  + ftanh(pv1.y + hv1.y) * av1.y
                  + ftanh(pv1.z + hv1.z) * av1.z
                  + ftanh(pv1.w + hv1.w) * av1.w;
#pragma unroll
        for (int off = 32; off > 0; off >>= 1) sum += __shfl_xor(sum, off);
        if (lane == 0) sc[s] = sum + ab0;
    }
    __syncthreads();

    float mx = -1e30f;
#pragma unroll
    for (int s = 0; s < Ss; ++s) mx = fmaxf(mx, sc[s]);
    float den = 0.f;
#pragma unroll
    for (int s = 0; s < Ss; ++s) den += __expf(sc[s] - mx);
    if (tid < Ss) wsm[tid] = __expf(sc[tid] - mx) / den * mask[tid];
    __syncthreads();
    float s2 = 0.f;
#pragma unroll
    for (int s = 0; s < Ss; ++s) s2 += wsm[s];
    const float inv = 1.f / (s2 + 1e-10f);

    const float4* f4 = (const float4*)feats;
    float4 acc = {0.f, 0.f, 0.f, 0.f};
#pragma unroll 6
    for (int s = 0; s < Ss; ++s) {
        float wv = wsm[s];
        float4 v = f4[s * 256 + tid];
        acc.x = fmaf(wv, v.x, acc.x);
        acc.y = fmaf(wv, v.y, acc.y);
        acc.z = fmaf(wv, v.z, acc.z);
        acc.w = fmaf(wv, v.w, acc.w);
    }
    acc.x *= inv; acc.y *= inv; acc.z *= inv; acc.w *= inv;
    ((float4*)outp)[tid] = acc;
}

// ---------------- human mean
__global__ __launch_bounds__(256) void human_mean_k(
    const float* __restrict__ hf, const float* __restrict__ bm, float* __restrict__ out)
{
    int idx = blockIdx.x * 256 + threadIdx.x;   // Bb*Hh
    int b = idx >> 10;
    float s = 0.f;
#pragma unroll
    for (int p = 0; p < 6; ++p) s += hf[((size_t)b * 6 + p) * Hh + (idx & 1023)];
    float ms = 0.f;
#pragma unroll
    for (int p = 0; p < 6; ++p) ms += bm[b * 6 + p];
    out[idx] = s / (ms + 1e-10f);
}

// ---------------- final combine: a_ori += (a_act + cal2)*g_h + a_obj*g_o
__global__ __launch_bounds__(256) void combine_k(
    const float* __restrict__ a_act, const float* __restrict__ cal2,
    const float* __restrict__ g_h, const float* __restrict__ a_obj,
    const float* __restrict__ g_o, float* a_ori)
{
    int idx = blockIdx.x * 256 + threadIdx.x;
    float att_human = a_act[idx] + cal2[idx];
    a_ori[idx] = att_human * g_h[idx] + a_obj[idx] * g_o[idx] + a_ori[idx];
}

extern "C" void kernel_launch(void* const* d_in, const int* in_sizes, int n_in,
                              void* d_out, int out_size, void* d_ws, size_t ws_size,
                              hipStream_t stream)
{
    (void)in_sizes; (void)n_in; (void)out_size; (void)ws_size;

    const float* xt = (const float*)d_in[0];
    const float* fc = (const float*)d_in[1];
    const float* att_feats[4] = {(const float*)d_in[2], (const float*)d_in[4],
                                 (const float*)d_in[6], (const float*)d_in[8]};
    const float* p_att[4]     = {(const float*)d_in[3], (const float*)d_in[5],
                                 (const float*)d_in[7], (const float*)d_in[9]};
    const float* masks[4]     = {(const float*)d_in[10], (const float*)d_in[11],
                                 (const float*)d_in[12], (const float*)d_in[12]};
    const float* human_feats = (const float*)d_in[13];
    const float* body_masks  = (const float*)d_in[14];
    const float* state_h = (const float*)d_in[15];
    const float* state_c = (const float*)d_in[16];
    const float* W_ih_att  = (const float*)d_in[17];
    const float* W_hh_att  = (const float*)d_in[18];
    const float* b_ih_att  = (const float*)d_in[19];
    const float* b_hh_att  = (const float*)d_in[20];
    const float* W_ih_lang = (const float*)d_in[21];
    const float* W_hh_lang = (const float*)d_in[22];
    const float* b_ih_lang = (const float*)d_in[23];
    const float* b_hh_lang = (const float*)d_in[24];
    const float* h2W[4] = {(const float*)d_in[25], (const float*)d_in[29],
                           (const float*)d_in[33], (const float*)d_in[37]};
    const float* h2b[4] = {(const float*)d_in[26], (const float*)d_in[30],
                           (const float*)d_in[34], (const float*)d_in[38]};
    const float* aWp[4] = {(const float*)d_in[27], (const float*)d_in[31],
                           (const float*)d_in[35], (const float*)d_in[39]};
    const float* abp[4] = {(const float*)d_in[28], (const float*)d_in[32],
                           (const float*)d_in[36], (const float*)d_in[40]};
    const float* hg_W = (const float*)d_in[41];
    const float* hg_b = (const float*)d_in[42];
    const float* ng_W = (const float*)d_in[43];
    const float* ng_b = (const float*)d_in[44];
    const float* c1W  = (const float*)d_in[45];
    const float* c1b  = (const float*)d_in[46];
    const float* c2W  = (const float*)d_in[47];
    const float* c2b  = (const float*)d_in[48];

    const int BH = Bb * Hh;
    float* out    = (float*)d_out;               // h_lang copy (output #1)
    float* h_att  = out + (size_t)BH;
    float* h_lang = out + (size_t)2 * BH;
    float* c_att  = out + (size_t)3 * BH;
    float* c_lang = out + (size_t)4 * BH;

    // ---- workspace carve-up (fp32 first, then bf16)
    float* wsf = (float*)d_ws;
    float* G        = wsf; wsf += (size_t)Bb * 4096;
    float* ATTH     = wsf; wsf += (size_t)Bb * 2048;      // [b][br*512+a]
    float* abuf     = wsf; wsf += (size_t)4 * BH;
    float* gate_h   = wsf; wsf += (size_t)BH;
    float* gate_o   = wsf; wsf += (size_t)BH;
    float* part0    = wsf; wsf += (size_t)BH;
    float* cal2     = wsf; wsf += (size_t)BH;
    float* bsum_att = wsf; wsf += 4096;
    float* bsum_lang= wsf; wsf += 4096;
    float* bcat_h2  = wsf; wsf += 2048;

    __hip_bfloat16* wsb = (__hip_bfloat16*)wsf;
    __hip_bfloat16* Wcat_att  = wsb; wsb += (size_t)4096 * 4096;
    __hip_bfloat16* Wcat_lang = wsb; wsb += (size_t)4096 * 4096;
    __hip_bfloat16* Wgh  = wsb; wsb += (size_t)1024 * 2048;
    __hip_bfloat16* Wgo  = wsb; wsb += (size_t)1024 * 2048;
    __hip_bfloat16* Wc1  = wsb; wsb += (size_t)1024 * 2048;
    __hip_bfloat16* Wc2  = wsb; wsb += (size_t)1024 * 1024;
    __hip_bfloat16* Wh2  = wsb; wsb += (size_t)2048 * 1024;
    __hip_bfloat16* A_att  = wsb; wsb += (size_t)Bb * 4096;
    __hip_bfloat16* A_lang = wsb; wsb += (size_t)Bb * 4096;
    __hip_bfloat16* A_gh   = wsb; wsb += (size_t)Bb * 2048;
    __hip_bfloat16* A_go   = wsb; wsb += (size_t)Bb * 2048;
    __hip_bfloat16* A_cal  = wsb; wsb += (size_t)Bb * 2048;
    __hip_bfloat16* hatt_bf = wsb; wsb += (size_t)Bb * 1024;
    __hip_bfloat16* cal1_bf = wsb; wsb += (size_t)Bb * 1024;

    const float* h0     = state_h;                 // state_h[0]
    const float* prev_h = state_h + (size_t)BH;    // state_h[1] (= state_h[-1])
    const float* c0     = state_c;
    const float* c1     = state_c + (size_t)BH;

    // ---- biases
    bias_sum_k<<<16, 256, 0, stream>>>(b_ih_att, b_hh_att, bsum_att, 4096);
    bias_sum_k<<<16, 256, 0, stream>>>(b_ih_lang, b_hh_lang, bsum_lang, 4096);
    bias_cat4_k<<<8, 256, 0, stream>>>(h2b[0], h2b[1], h2b[2], h2b[3], bcat_h2);

    // ---- weight conversions (fp32 -> bf16, with Wih|Whh K-concat)
    cvt_cat_bf16<<<8192, 256, 0, stream>>>(
        aseg2(W_ih_att, 3072, 0, 3072, W_hh_att, 1024, 0, 4096), Wcat_att, 4096, 512);
    cvt_cat_bf16<<<8192, 256, 0, stream>>>(
        aseg2(W_ih_lang, 3072, 0, 3072, W_hh_lang, 1024, 0, 4096), Wcat_lang, 4096, 512);
    cvt_cat_bf16<<<1024, 256, 0, stream>>>(aseg1(hg_W, 2048, 0, 2048), Wgh, 1024, 256);
    cvt_cat_bf16<<<1024, 256, 0, stream>>>(aseg1(ng_W, 2048, 0, 2048), Wgo, 1024, 256);
    cvt_cat_bf16<<<1024, 256, 0, stream>>>(aseg1(c1W, 2048, 0, 2048), Wc1, 1024, 256);
    cvt_cat_bf16<<<512, 256, 0, stream>>>(aseg1(c2W, 1024, 0, 1024), Wc2, 1024, 128);
    for (int br = 0; br < 4; ++br)
        cvt_cat_bf16<<<256, 256, 0, stream>>>(
            aseg1(h2W[br], 1024, 0, 1024), Wh2 + (size_t)br * 512 * 1024, 512, 128);

    // ---- attention LSTM
    cvt_cat_bf16<<<1024, 256, 0, stream>>>(
        aseg4(prev_h, fc, xt, h0, Hh, 3072, Hh, Hh, 0, 0, 0, 0), A_att, Bb, 512);
    gemm_mfma<128, 128, 0, 0><<<dim3(4, 32), 256, 0, stream>>>(
        A_att, Wcat_att, bsum_att, G, nullptr, Bb, 4096, 4096);
    lstm_cell_k<<<2048, 256, 0, stream>>>(G, c0, h_att, c_att, nullptr, hatt_bf);

    // ---- human feats mean
    human_mean_k<<<2048, 256, 0, stream>>>(human_feats, body_masks, part0);

    // ---- h2att GEMM (4 branches packed along N)
    gemm_mfma<64, 64, 0, 0><<<dim3(8, 32), 256, 0, stream>>>(
        hatt_bf, Wh2, bcat_h2, ATTH, nullptr, Bb, 2048, 1024);

    // ---- fused attention, 4 branches
    {
        AttPtrs P;
        for (int i = 0; i < 4; ++i) {
            P.p_att[i] = p_att[i]; P.feats[i] = att_feats[i];
            P.mask[i] = masks[i]; P.aW[i] = aWp[i]; P.ab[i] = abp[i];
        }
        att_fused_k<<<dim3(Bb, 4), 256, 0, stream>>>(P, ATTH, abuf);
    }

    // ---- gates
    cvt_cat_bf16<<<512, 256, 0, stream>>>(
        aseg2(fc, 3072, 1024, 1024, h_att, Hh, 0, 2048), A_gh, Bb, 256);
    cvt_cat_bf16<<<512, 256, 0, stream>>>(
        aseg2(fc, 3072, 2048, 1024, h_att, Hh, 0, 2048), A_go, Bb, 256);
    gemm_mfma<64, 64, 2, 0><<<dim3(8, 16), 256, 0, stream>>>(
        A_gh, Wgh, hg_b, gate_h, nullptr, Bb, 1024, 2048);
    gemm_mfma<64, 64, 2, 0><<<dim3(8, 16), 256, 0, stream>>>(
        A_go, Wgo, ng_b, gate_o, nullptr, Bb, 1024, 2048);

    // ---- cali MLP
    cvt_cat_bf16<<<512, 256, 0, stream>>>(
        aseg2(part0, Hh, 0, 1024, abuf /*att_activity*/, Hh, 0, 2048), A_cal, Bb, 256);
    gemm_mfma<64, 64, 1, 1><<<dim3(8, 16), 256, 0, stream>>>(
        A_cal, Wc1, c1b, nullptr, cal1_bf, Bb, 1024, 2048);
    gemm_mfma<64, 64, 0, 0><<<dim3(8, 16), 256, 0, stream>>>(
        cal1_bf, Wc2, c2b, cal2, nullptr, Bb, 1024, 1024);

    // ---- att_ori_final = (att_act + cal2)*gate_h + att_obj*gate_o + att_ori
    combine_k<<<2048, 256, 0, stream>>>(
        abuf, cal2, gate_h, abuf + BH, gate_o, abuf + 2 * (size_t)BH);

    // ---- language LSTM
    cvt_cat_bf16<<<1024, 256, 0, stream>>>(
        aseg4(abuf + 3 * (size_t)BH, abuf + 2 * (size_t)BH, h_att, prev_h,
              Hh, Hh, Hh, Hh, 0, 0, 0, 0), A_lang, Bb, 512);
    gemm_mfma<128, 128, 0, 0><<<dim3(4, 32), 256, 0, stream>>>(
        A_lang, Wcat_lang, bsum_lang, G, nullptr, Bb, 4096, 4096);
    lstm_cell_k<<<2048, 256, 0, stream>>>(G, c1, h_lang, c_lang, out, nullptr);
}